// Round 9
// baseline (113.066 us; speedup 1.0000x reference)
//
#include <hip/hip_runtime.h>

#define NB   1024   // blocks (one wave each)
#define NGEN 4      // generations (64-elem chunks) per block

// Fused single kernel. One wave per block, zero barriers. Each block owns a
// contiguous 4-chunk region; per generation: ds_write staged regs -> LDS,
// ISSUE next generation's coalesced float4 global loads (they land during
// compute), then compute from LDS. vmcnt drains only at the next ds_write,
// so memory and VALU overlap across generations (the R3-R7 serialization
// wall). Final mean fused via threadfence + atomic-counter last-block.
__global__ __launch_bounds__(64, 1) void cg_fused_kernel(
    const float* __restrict__ D1, const float* __restrict__ D2,
    const float* __restrict__ D3, const float* __restrict__ cg,
    float* partials, int* counter, float* out, float inv)
{
    __shared__ __align__(16) float s1[64 * 9];    //  2304 B
    __shared__ __align__(16) float s2[64 * 25];   //  6400 B
    __shared__ __align__(16) float s3[64 * 49];   // 12544 B (21.25 KB total)

    const int l   = threadIdx.x;     // lane 0..63
    const int blk = blockIdx.x;

    float4 p1[3], p2[7], p3[13];     // 92 VGPRs of prefetch state (intentional)

    // ---- prologue: prefetch generation 0 ----
    {
        const size_t ch = (size_t)blk * NGEN;
        const float4* g1 = (const float4*)(D1 + ch * 576);
        const float4* g2 = (const float4*)(D2 + ch * 1600);
        const float4* g3 = (const float4*)(D3 + ch * 3136);
        #pragma unroll
        for (int k = 0; k < 3; ++k)  { int i = k * 64 + l; if (i < 144) p1[k] = g1[i]; }
        #pragma unroll
        for (int k = 0; k < 7; ++k)  { int i = k * 64 + l; if (i < 400) p2[k] = g2[i]; }
        #pragma unroll
        for (int k = 0; k < 13; ++k) { int i = k * 64 + l; if (i < 784) p3[k] = g3[i]; }
    }

    float acc = 0.0f;

    #pragma unroll 1
    for (int g = 0; g < NGEN; ++g) {
        // ---- stage current generation regs -> LDS (waits on its vmcnt here) ----
        {
            float4* t1 = (float4*)s1;
            float4* t2 = (float4*)s2;
            float4* t3 = (float4*)s3;
            #pragma unroll
            for (int k = 0; k < 3; ++k)  { int i = k * 64 + l; if (i < 144) t1[i] = p1[k]; }
            #pragma unroll
            for (int k = 0; k < 7; ++k)  { int i = k * 64 + l; if (i < 400) t2[i] = p2[k]; }
            #pragma unroll
            for (int k = 0; k < 13; ++k) { int i = k * 64 + l; if (i < 784) t3[i] = p3[k]; }
        }

        // ---- issue NEXT generation's loads (land during compute below) ----
        if (g + 1 < NGEN) {
            const size_t ch = (size_t)blk * NGEN + g + 1;
            const float4* g1 = (const float4*)(D1 + ch * 576);
            const float4* g2 = (const float4*)(D2 + ch * 1600);
            const float4* g3 = (const float4*)(D3 + ch * 3136);
            #pragma unroll
            for (int k = 0; k < 3; ++k)  { int i = k * 64 + l; if (i < 144) p1[k] = g1[i]; }
            #pragma unroll
            for (int k = 0; k < 7; ++k)  { int i = k * 64 + l; if (i < 400) p2[k] = g2[i]; }
            #pragma unroll
            for (int k = 0; k < 13; ++k) { int i = k * 64 + l; if (i < 784) p3[k] = g3[i]; }
        }

        // ---- compute generation g from LDS (strides 9/25/49: free 2-way) ----
        float d1r[9];
        #pragma unroll
        for (int i = 0; i < 9; ++i)  d1r[i] = s1[l * 9 + i];
        float d2r[25];
        #pragma unroll
        for (int j = 0; j < 25; ++j) d2r[j] = s2[l * 25 + j];

        #pragma unroll
        for (int c = 0; c < 7; ++c) {
            float d3c[7];
            #pragma unroll
            for (int i = 0; i < 7; ++i) d3c[i] = s3[l * 49 + i * 7 + c];

            #pragma unroll
            for (int a = 0; a < 3; ++a) {
                float U[5];
                #pragma unroll
                for (int j = 0; j < 5; ++j)
                    U[j] = fmaf(d1r[a * 3 + 2], cg[70 + j * 7 + c],
                           fmaf(d1r[a * 3 + 1], cg[35 + j * 7 + c],
                                d1r[a * 3 + 0] * cg[      j * 7 + c]));
                #pragma unroll
                for (int b = 0; b < 5; ++b) {
                    float L = d2r[b * 5] * U[0];
                    #pragma unroll
                    for (int j = 1; j < 5; ++j) L = fmaf(d2r[b * 5 + j], U[j], L);
                    float R = cg[(a * 5 + b) * 7] * d3c[0];
                    #pragma unroll
                    for (int i = 1; i < 7; ++i) R = fmaf(cg[(a * 5 + b) * 7 + i], d3c[i], R);
                    const float r = L - R;
                    acc = fmaf(r, r, acc);
                }
            }
        }
    }

    // ---- per-wave reduce -> partial ----
    #pragma unroll
    for (int off = 32; off > 0; off >>= 1)
        acc += __shfl_down(acc, off, 64);

    int last = 0;
    if (l == 0) {
        partials[blk] = acc;
        __threadfence();                          // release partials
        if (atomicAdd(counter, 1) == NB - 1) last = 1;
    }
    last = __shfl(last, 0, 64);

    // ---- last block: deterministic final reduce (fixed order) ----
    if (last) {
        __threadfence();                          // acquire all partials
        float s = 0.0f;
        for (int i = l; i < NB; i += 64) s += partials[i];
        #pragma unroll
        for (int off = 32; off > 0; off >>= 1)
            s += __shfl_down(s, off, 64);
        if (l == 0) out[0] = s * inv;
    }
}

extern "C" void kernel_launch(void* const* d_in, const int* in_sizes, int n_in,
                              void* d_out, int out_size, void* d_ws, size_t ws_size,
                              hipStream_t stream)
{
    const float* D1 = (const float*)d_in[0];
    const float* D2 = (const float*)d_in[1];
    const float* D3 = (const float*)d_in[2];
    const float* cg = (const float*)d_in[3];
    float* out      = (float*)d_out;

    float* partials = (float*)d_ws;                      // NB floats = 4 KB
    int*   counter  = (int*)((char*)d_ws + NB * 4);      // 4 bytes after

    const int batch = in_sizes[0] / 9;                   // 262144
    const float inv = 1.0f / ((float)batch * 105.0f);

    hipMemsetAsync(counter, 0, sizeof(int), stream);     // reset each launch (graph node)
    cg_fused_kernel<<<NB, 64, 0, stream>>>(D1, D2, D3, cg,
                                           partials, counter, out, inv);
}